// Round 6
// baseline (1682.832 us; speedup 1.0000x reference)
//
#include <hip/hip_runtime.h>

// Problem constants (match reference)
#define BATCH 8
#define NPTS  32768
#define DIM   256
#define NSAMP 64      // NPOINT (fps samples)
#define NNBR  8       // ball-query neighbors
#define LN_EPS 1e-5f

// Inter-kernel buffers as device globals (no d_ws dependence).
__device__ float g_sample_coor[BATCH * NSAMP * 3];
__device__ float g_diff_coor[BATCH * NSAMP * 3];
__device__ float g_qbuf[BATCH * NSAMP * DIM];
__device__ float g_kbuf[BATCH * NSAMP * DIM];
__device__ int   g_fidx[BATCH * NSAMP];

// I/O dtypes (forensically established):
//  - inputs  = FLOAT32 storage (R2: reading as bf16 created sNaN patterns -> NaN)
//  - outputs = FLOAT32 storage (R3-R5: bf16 ushort writes gave deterministic
//    6.72 error == interleaved-bf16-read-as-f32 signature; index logic proven
//    robust under f32-asm/f32-compiler/f64 arithmetic)

// Index-critical distances in f64: exact for f32 inputs (diff exact, square
// 48<53 bits), contraction-immune, and matches any reasonable np ref rounding.
__device__ __forceinline__ double dist2_64(float px, float py, float pz,
                                           float cx, float cy, float cz) {
    double dx = (double)px - (double)cx;
    double dy = (double)py - (double)cy;
    double dz = (double)pz - (double)cz;
    return (dx * dx + dy * dy) + dz * dz;   // numpy's (x^2+y^2)+z^2 order
}

// ============================================================================
// Kernel A: farthest-point sampling. One block per batch, 1024 threads,
// 32 points/thread; dist[] kept in f64. Argmax tie-break: lowest index.
// ============================================================================
__global__ __launch_bounds__(1024) void fps_kernel(
    const float* __restrict__ coor)
{
    const int b = blockIdx.x;
    const int t = threadIdx.x;
    const float* cb = coor + (size_t)b * NPTS * 3;

    double dist[32];
#pragma unroll
    for (int k = 0; k < 32; ++k) dist[k] = 1e10;

    __shared__ float  s_ctr[3];
    __shared__ double s_rv[16];
    __shared__ int    s_ri[16];

    if (t == 0) { s_ctr[0] = cb[0]; s_ctr[1] = cb[1]; s_ctr[2] = cb[2]; }
    __syncthreads();

    int cidx = 0;                       // only meaningful on t==0
    for (int s = 0; s < NSAMP; ++s) {
        float cx = s_ctr[0], cy = s_ctr[1], cz = s_ctr[2];
        if (t == 0) {
            g_fidx[b * NSAMP + s] = cidx;
            g_sample_coor[(b * NSAMP + s) * 3 + 0] = cx;
            g_sample_coor[(b * NSAMP + s) * 3 + 1] = cy;
            g_sample_coor[(b * NSAMP + s) * 3 + 2] = cz;
        }
        if (s == NSAMP - 1) break;

        double best = -1.0; int bidx = 0;
#pragma unroll
        for (int k = 0; k < 32; ++k) {
            int p = (k << 10) + t;
            double d2 = dist2_64(cb[p * 3 + 0], cb[p * 3 + 1], cb[p * 3 + 2],
                                 cx, cy, cz);
            double nd = fmin(dist[k], d2);
            dist[k] = nd;
            if (nd > best) { best = nd; bidx = p; }  // strict > keeps lowest p
        }
        // wave butterfly argmax with lowest-index tie-break
#pragma unroll
        for (int off = 32; off > 0; off >>= 1) {
            double ov = __shfl_xor(best, off);
            int    oi = __shfl_xor(bidx, off);
            if (ov > best || (ov == best && oi < bidx)) { best = ov; bidx = oi; }
        }
        if ((t & 63) == 0) { s_rv[t >> 6] = best; s_ri[t >> 6] = bidx; }
        __syncthreads();
        if (t == 0) {
            double bv = s_rv[0]; int bi = s_ri[0];
#pragma unroll
            for (int w = 1; w < 16; ++w) {
                double v = s_rv[w]; int i = s_ri[w];
                if (v > bv || (v == bv && i < bi)) { bv = v; bi = i; }
            }
            cidx = bi;
            s_ctr[0] = cb[bi * 3 + 0];
            s_ctr[1] = cb[bi * 3 + 1];
            s_ctr[2] = cb[bi * 3 + 2];
        }
        __syncthreads();
    }
}

// ============================================================================
// Kernel B: ball query (first-8 within radius by index order, f64 distance,
// early exit) + grouped-feature max (out0 = global_x, f32) + diff_coor mean.
// One wave per (b,s) center.
// ============================================================================
__global__ __launch_bounds__(64) void ballquery_kernel(
    const float* __restrict__ coor,
    const float* __restrict__ x,
    float* __restrict__ out0)
{
    const int bid = blockIdx.x;
    const int b = bid >> 6, s = bid & 63;
    const int lane = threadIdx.x;
    const float* cb = coor + (size_t)b * NPTS * 3;

    const float cx = g_sample_coor[(b * NSAMP + s) * 3 + 0];
    const float cy = g_sample_coor[(b * NSAMP + s) * 3 + 1];
    const float cz = g_sample_coor[(b * NSAMP + s) * 3 + 2];

    __shared__ int s_nidx[NNBR];
    int found = 0;
    for (int ch = 0; ch < NPTS / 64 && found < NNBR; ++ch) {
        int p = (ch << 6) + lane;
        double d2 = dist2_64(cb[p * 3 + 0], cb[p * 3 + 1], cb[p * 3 + 2],
                             cx, cy, cz);
        unsigned long long m = __ballot(d2 < 16.0);   // strict <
        while (m && found < NNBR) {                   // wave-uniform
            int bpos = __ffsll(m) - 1;
            if (lane == 0) s_nidx[found] = (ch << 6) + bpos;
            ++found;
            m &= m - 1;
        }
    }
    if (lane == 0) {                         // pad with first hit (or 0 if none)
        if (found == 0) { s_nidx[0] = 0; found = 1; }
        int f0 = s_nidx[0];
        for (int j = found; j < NNBR; ++j) s_nidx[j] = f0;
    }
    __syncthreads();

    // grouped-feature max -> out0 (4 channels/lane; f32 in, f32 out)
    int c0 = lane * 4;
    float a0 = -1e30f, a1 = -1e30f, a2 = -1e30f, a3 = -1e30f;
#pragma unroll
    for (int j = 0; j < NNBR; ++j) {
        const float4 v = *(const float4*)(x + ((size_t)b * NPTS + s_nidx[j]) * DIM + c0);
        a0 = fmaxf(a0, v.x); a1 = fmaxf(a1, v.y);
        a2 = fmaxf(a2, v.z); a3 = fmaxf(a3, v.w);
    }
    float4 o; o.x = a0; o.y = a1; o.z = a2; o.w = a3;
    *(float4*)(out0 + ((size_t)(b * NSAMP + s)) * DIM + c0) = o;

    // diff_coor = mean_j (p_j - c)   (continuous path)
    if (lane < 3) {
        float sum = 0.f;
#pragma unroll
        for (int j = 0; j < NNBR; ++j) {
            float pv = cb[s_nidx[j] * 3 + lane];
            sum += pv - ((lane == 0) ? cx : (lane == 1) ? cy : cz);
        }
        g_diff_coor[(b * NSAMP + s) * 3 + lane] = sum * 0.125f;
    }
}

// ============================================================================
// Kernel C1: LayerNorm + row @ W^T. One block per (b, s, which) row.
// which==0: q from diff_x = global_x(out0) - sample_x ; which==1: k from sample_x.
// ============================================================================
__global__ __launch_bounds__(256) void ln_gemm_kernel(
    const float* __restrict__ x,
    const float* __restrict__ out0,
    const float* __restrict__ Wq,
    const float* __restrict__ Wk,
    const float* __restrict__ gq, const float* __restrict__ bq,
    const float* __restrict__ gk, const float* __restrict__ bk)
{
    const int bid = blockIdx.x;
    const int which = bid & 1;
    const int s = (bid >> 1) & 63;
    const int b = bid >> 7;
    const int c = threadIdx.x;

    const int fidx = g_fidx[b * NSAMP + s];
    float xs = x[((size_t)b * NPTS + fidx) * DIM + c];
    float r  = which ? xs : (out0[(size_t)(b * NSAMP + s) * DIM + c] - xs);

    __shared__ float red[4];
    __shared__ float ln[DIM];

    float sum = r;
#pragma unroll
    for (int off = 32; off; off >>= 1) sum += __shfl_xor(sum, off);
    int wid = c >> 6;
    if ((c & 63) == 0) red[wid] = sum;
    __syncthreads();
    float mean = (red[0] + red[1] + red[2] + red[3]) * (1.0f / DIM);
    float d = r - mean;
    float vs = d * d;
#pragma unroll
    for (int off = 32; off; off >>= 1) vs += __shfl_xor(vs, off);
    __syncthreads();
    if ((c & 63) == 0) red[wid] = vs;
    __syncthreads();
    float var = (red[0] + red[1] + red[2] + red[3]) * (1.0f / DIM);
    float rs = 1.0f / sqrtf(var + LN_EPS);

    ln[c] = d * rs * (which ? gk[c] : gq[c]) + (which ? bk[c] : bq[c]);
    __syncthreads();

    const float* W = (which ? Wk : Wq) + (size_t)c * DIM;
    float acc = 0.f;
#pragma unroll 4
    for (int i = 0; i < DIM; i += 4) {
        float4 wv = *(const float4*)(W + i);      // 16B aligned
        acc = fmaf(ln[i + 0], wv.x, acc);
        acc = fmaf(ln[i + 1], wv.y, acc);
        acc = fmaf(ln[i + 2], wv.z, acc);
        acc = fmaf(ln[i + 3], wv.w, acc);
    }
    (which ? g_kbuf : g_qbuf)[(size_t)(b * NSAMP + s) * DIM + c] = acc;
}

// ============================================================================
// Kernel C2: attention per batch: logits (64x64) -> softmax -> @v -> out1.
// v is the [B,3,S]->[B,S,3] memory reinterpretation of diff_coor.
// ============================================================================
__global__ __launch_bounds__(1024) void attn_kernel(
    float* __restrict__ out1)
{
    const int b = blockIdx.x;
    const int tid = threadIdx.x;
    __shared__ float att[64][64];
    __shared__ float vv[64][3];

    // logits: thread computes row i, cols j0..j0+3
    {
        const int i  = tid >> 4;
        const int j0 = (tid & 15) << 2;
        const float* qr = g_qbuf + (size_t)(b * NSAMP + i) * DIM;
        const float* k0 = g_kbuf + (size_t)(b * NSAMP + j0) * DIM;
        float a0 = 0, a1 = 0, a2 = 0, a3 = 0;
        for (int ii = 0; ii < DIM; ii += 4) {
            float4 qv = *(const float4*)(qr + ii);
            float4 v0 = *(const float4*)(k0 + ii);
            float4 v1 = *(const float4*)(k0 + DIM + ii);
            float4 v2 = *(const float4*)(k0 + 2 * DIM + ii);
            float4 v3 = *(const float4*)(k0 + 3 * DIM + ii);
            a0 += qv.x * v0.x + qv.y * v0.y + qv.z * v0.z + qv.w * v0.w;
            a1 += qv.x * v1.x + qv.y * v1.y + qv.z * v1.z + qv.w * v1.w;
            a2 += qv.x * v2.x + qv.y * v2.y + qv.z * v2.z + qv.w * v2.w;
            a3 += qv.x * v3.x + qv.y * v3.y + qv.z * v3.z + qv.w * v3.w;
        }
        att[i][j0 + 0] = a0 * 0.0625f;   // scale = 1/sqrt(256)
        att[i][j0 + 1] = a1 * 0.0625f;
        att[i][j0 + 2] = a2 * 0.0625f;
        att[i][j0 + 3] = a3 * 0.0625f;
    }
    __syncthreads();

    const int wv_ = tid >> 6, lane = tid & 63;
    // softmax rows (wave per row, 4 rows/wave)
    for (int r = wv_; r < 64; r += 16) {
        float v = att[r][lane];
        float m = v;
#pragma unroll
        for (int off = 32; off; off >>= 1) m = fmaxf(m, __shfl_xor(m, off));
        float e = expf(v - m);
        float ss = e;
#pragma unroll
        for (int off = 32; off; off >>= 1) ss += __shfl_xor(ss, off);
        att[r][lane] = e / ss;
    }
    // build v: flat t = m*3+d reads diff_coor[b, t%64, t/64]
    if (tid < 192) {
        int m = tid / 3, d = tid - 3 * m;
        vv[m][d] = g_diff_coor[(size_t)(b * NSAMP + (tid & 63)) * 3 + (tid >> 6)];
    }
    __syncthreads();

    // coor_2 = attn @ v ; out1 = sample_coor + coor_2  (f32 out)
    for (int r = wv_; r < 64; r += 16) {
        float a = att[r][lane];
        float s0 = a * vv[lane][0];
        float s1 = a * vv[lane][1];
        float s2 = a * vv[lane][2];
#pragma unroll
        for (int off = 32; off; off >>= 1) {
            s0 += __shfl_xor(s0, off);
            s1 += __shfl_xor(s1, off);
            s2 += __shfl_xor(s2, off);
        }
        if (lane == 0) {
            int o = (b * NSAMP + r) * 3;
            out1[o + 0] = g_sample_coor[o + 0] + s0;
            out1[o + 1] = g_sample_coor[o + 1] + s1;
            out1[o + 2] = g_sample_coor[o + 2] + s2;
        }
    }
}

// ============================================================================
extern "C" void kernel_launch(void* const* d_in, const int* in_sizes, int n_in,
                              void* d_out, int out_size, void* d_ws, size_t ws_size,
                              hipStream_t stream)
{
    const float* x    = (const float*)d_in[0];
    const float* coor = (const float*)d_in[1];
    if (in_sizes[0] == BATCH * NPTS * 3) {   // defensive size-based resolution
        x    = (const float*)d_in[1];
        coor = (const float*)d_in[0];
    }
    const float* Wq   = (const float*)d_in[2];
    const float* Wk   = (const float*)d_in[3];
    const float* gq   = (const float*)d_in[4];
    const float* bq   = (const float*)d_in[5];
    const float* gk   = (const float*)d_in[6];
    const float* bk   = (const float*)d_in[7];

    float* out0 = (float*)d_out;                          // [B,S,C] f32
    float* out1 = out0 + (size_t)BATCH * NSAMP * DIM;     // [B,S,3] f32

    hipLaunchKernelGGL(fps_kernel, dim3(BATCH), dim3(1024), 0, stream, coor);
    hipLaunchKernelGGL(ballquery_kernel, dim3(BATCH * NSAMP), dim3(64), 0, stream,
                       coor, x, out0);
    hipLaunchKernelGGL(ln_gemm_kernel, dim3(BATCH * NSAMP * 2), dim3(256), 0, stream,
                       x, out0, Wq, Wk, gq, bq, gk, bk);
    hipLaunchKernelGGL(attn_kernel, dim3(BATCH), dim3(1024), 0, stream, out1);
}